// Round 1
// baseline (40446.548 us; speedup 1.0000x reference)
//
#include <hip/hip_runtime.h>

#define NHID 1024
#define NB 128      // batch
#define NIN 64
#define TSTEPS 512
#define NBLK 128
#define NTHR 256

typedef __attribute__((ext_vector_type(8))) short short8v;
typedef __attribute__((ext_vector_type(4))) float f32x4;

__device__ __forceinline__ short8v ld8(const unsigned short* p) {
  return *reinterpret_cast<const short8v*>(p);
}

__device__ __forceinline__ unsigned short f2b(float x) {
  union { float f; unsigned u; } v; v.f = x;
  unsigned r = v.u + 0x7fffu + ((v.u >> 16) & 1u);
  return (unsigned short)(r >> 16);
}

struct GruParams {
  const unsigned short* u;                    // [T][B][NIN] bf16
  const unsigned short* WhzT; const unsigned short* WhrT; const unsigned short* WhhT; // [NHID][NHID] bf16 (transposed: [n][k])
  const unsigned short* WuzT; const unsigned short* WurT; const unsigned short* WuhT; // [NHID][NIN] bf16
  const float* bz; const float* br; const float* bh;
  float* h;                                   // [B][NHID] f32 (lives in d_out+1280)
  unsigned short* hb;                         // bf16 copy of h
  unsigned short* sb;                         // bf16 r*h
  unsigned* cnt; unsigned* gen;
};

__device__ __forceinline__ void gridbar(unsigned* cnt, unsigned* gen) {
  __threadfence();          // release: my global writes -> visible (L2 wb on gfx950 agent scope)
  __syncthreads();
  if (threadIdx.x == 0) {
    unsigned g = __hip_atomic_load(gen, __ATOMIC_RELAXED, __HIP_MEMORY_SCOPE_AGENT);
    unsigned a = __hip_atomic_fetch_add(cnt, 1u, __ATOMIC_ACQ_REL, __HIP_MEMORY_SCOPE_AGENT);
    if (a == NBLK - 1) {
      __hip_atomic_store(cnt, 0u, __ATOMIC_RELAXED, __HIP_MEMORY_SCOPE_AGENT);
      __hip_atomic_fetch_add(gen, 1u, __ATOMIC_RELEASE, __HIP_MEMORY_SCOPE_AGENT);
    } else {
      // bounded spin: never triggers unless a real deadlock; avoids infinite hang
      for (long long it = 0; it < (1ll << 33); ++it) {
        if (__hip_atomic_load(gen, __ATOMIC_RELAXED, __HIP_MEMORY_SCOPE_AGENT) != g) break;
        __builtin_amdgcn_s_sleep(1);
      }
    }
  }
  __syncthreads();
  __threadfence();          // acquire: invalidate stale lines before reading peers' data
}

// Persistent GRU kernel. Block b owns columns [16*(b&63), +16) of nhid for
// row-half (b>>6). Wave w handles rows 64*(b>>6)+16*w .. +15 (one 16x16 MFMA tile).
__global__ __launch_bounds__(NTHR, 1) void gru_main(GruParams p) {
  const int tid  = threadIdx.x;
  const int lane = tid & 63;
  const int w    = tid >> 6;
  const int mg   = blockIdx.x >> 6;   // 0..1 row half
  const int cgi  = blockIdx.x & 63;   // column group
  const int R    = mg * 64 + w * 16;  // row tile base
  const int C    = cgi * 16;          // col base
  const int lr   = lane & 15;         // A-row / B-col within tile
  const int lk   = (lane >> 4) * 8;   // k offset of this lane's 8 elems

  // zero h (h0 = 0), then barrier
  for (int i = blockIdx.x * NTHR + tid; i < NB * NHID; i += NBLK * NTHR) {
    p.h[i] = 0.f;
    p.hb[i] = 0;
  }
  gridbar(p.cnt, p.gen);

  const float bzv = p.bz[C + lr];
  const float brv = p.br[C + lr];
  const float bhv = p.bh[C + lr];

  const unsigned short* wz  = p.WhzT + (size_t)(C + lr) * NHID + lk;
  const unsigned short* wr  = p.WhrT + (size_t)(C + lr) * NHID + lk;
  const unsigned short* wh  = p.WhhT + (size_t)(C + lr) * NHID + lk;
  const unsigned short* wuz = p.WuzT + (C + lr) * NIN + lk;
  const unsigned short* wur = p.WurT + (C + lr) * NIN + lk;
  const unsigned short* wuh = p.WuhT + (C + lr) * NIN + lk;
  const unsigned short* ahp = p.hb + (size_t)(R + lr) * NHID + lk;  // A frag: h row
  const unsigned short* asp = p.sb + (size_t)(R + lr) * NHID + lk;  // A frag: s row

  // D layout (16x16x32): lane holds D[(lane>>4)*4+i][lane&15]
  const int orow = R + (lane >> 4) * 4;
  const int ocol = C + lr;

  float zreg[4], hreg[4];

  for (int t = 0; t < TSTEPS; ++t) {
    const unsigned short* au = p.u + ((size_t)t * NB + (R + lr)) * NIN + lk;

    // ---- phase A: z = sigmoid(u@Wuz + b_z + h@Whz); r likewise; s = r*h ----
    f32x4 az = {0.f, 0.f, 0.f, 0.f};
    f32x4 ar = {0.f, 0.f, 0.f, 0.f};
#pragma unroll 4
    for (int k = 0; k < NHID; k += 32) {
      short8v a = ld8(ahp + k);
      az = __builtin_amdgcn_mfma_f32_16x16x32_bf16(a, ld8(wz + k), az, 0, 0, 0);
      ar = __builtin_amdgcn_mfma_f32_16x16x32_bf16(a, ld8(wr + k), ar, 0, 0, 0);
    }
#pragma unroll
    for (int k = 0; k < NIN; k += 32) {
      short8v a = ld8(au + k);
      az = __builtin_amdgcn_mfma_f32_16x16x32_bf16(a, ld8(wuz + k), az, 0, 0, 0);
      ar = __builtin_amdgcn_mfma_f32_16x16x32_bf16(a, ld8(wur + k), ar, 0, 0, 0);
    }
#pragma unroll
    for (int i = 0; i < 4; ++i) {
      int row = orow + i;
      float z = 1.f / (1.f + expf(-(az[i] + bzv)));
      float r = 1.f / (1.f + expf(-(ar[i] + brv)));
      float hold = p.h[row * NHID + ocol];
      zreg[i] = z;
      hreg[i] = hold;
      p.sb[row * NHID + ocol] = f2b(r * hold);
    }
    gridbar(p.cnt, p.gen);

    // ---- phase B: h_tilde = tanh(u@Wuh + b_h + s@Whh); h = (1-z)h + z*h_tilde ----
    f32x4 ac = {0.f, 0.f, 0.f, 0.f};
#pragma unroll 4
    for (int k = 0; k < NHID; k += 32) {
      ac = __builtin_amdgcn_mfma_f32_16x16x32_bf16(ld8(asp + k), ld8(wh + k), ac, 0, 0, 0);
    }
#pragma unroll
    for (int k = 0; k < NIN; k += 32) {
      ac = __builtin_amdgcn_mfma_f32_16x16x32_bf16(ld8(au + k), ld8(wuh + k), ac, 0, 0, 0);
    }
#pragma unroll
    for (int i = 0; i < 4; ++i) {
      int row = orow + i;
      float ht = tanhf(ac[i] + bhv);
      float hn = (1.f - zreg[i]) * hreg[i] + zreg[i] * ht;
      p.h[row * NHID + ocol] = hn;
      p.hb[row * NHID + ocol] = f2b(hn);
    }
    gridbar(p.cnt, p.gen);
  }
}

// out[c*R + r] = bf16(in[r*C + c])  (W[k][n] -> WT[n][k])
__global__ void k_transpose_bf16(const float* in, unsigned short* out, int R, int C) {
  int idx = blockIdx.x * 256 + threadIdx.x;
  if (idx < R * C) {
    int r = idx / C, c = idx % C;
    out[(size_t)c * R + r] = f2b(in[idx]);
  }
}

__global__ void k_convert_bf16(const float* in, unsigned short* out, int n) {
  for (int i = blockIdx.x * 256 + threadIdx.x; i < n; i += gridDim.x * 256)
    out[i] = f2b(in[i]);
}

// logits = h_final @ W_hy + b_y ; one block (64 lanes) per batch row
__global__ void k_logits(const float* __restrict__ h, const float* __restrict__ Why,
                         const float* __restrict__ by, float* __restrict__ out) {
  int row = blockIdx.x;
  int lane = threadIdx.x;
  float acc[10];
#pragma unroll
  for (int j = 0; j < 10; ++j) acc[j] = 0.f;
  for (int k = lane; k < NHID; k += 64) {
    float hv = h[row * NHID + k];
#pragma unroll
    for (int j = 0; j < 10; ++j) acc[j] += hv * Why[k * 10 + j];
  }
#pragma unroll
  for (int j = 0; j < 10; ++j)
    for (int off = 32; off; off >>= 1) acc[j] += __shfl_down(acc[j], off);
  if (lane == 0) {
#pragma unroll
    for (int j = 0; j < 10; ++j) out[row * 10 + j] = acc[j] + by[j];
  }
}

extern "C" void kernel_launch(void* const* d_in, const int* in_sizes, int n_in,
                              void* d_out, int out_size, void* d_ws, size_t ws_size,
                              hipStream_t stream) {
  (void)in_sizes; (void)n_in; (void)out_size; (void)ws_size;
  const float* u   = (const float*)d_in[0];
  const float* Wuz = (const float*)d_in[1];
  const float* Whz = (const float*)d_in[2];
  const float* bz  = (const float*)d_in[3];
  const float* Wur = (const float*)d_in[4];
  const float* Whr = (const float*)d_in[5];
  const float* br  = (const float*)d_in[6];
  const float* Wuh = (const float*)d_in[7];
  const float* Whh = (const float*)d_in[8];
  const float* bh  = (const float*)d_in[9];
  const float* Why = (const float*)d_in[10];
  const float* by  = (const float*)d_in[11];

  char* ws = (char*)d_ws;
  size_t off = 0;
  auto alloc = [&](size_t bytes) { char* p = ws + off; off += (bytes + 255) & ~255ull; return p; };
  unsigned short* WhzT = (unsigned short*)alloc((size_t)NHID * NHID * 2);
  unsigned short* WhrT = (unsigned short*)alloc((size_t)NHID * NHID * 2);
  unsigned short* WhhT = (unsigned short*)alloc((size_t)NHID * NHID * 2);
  unsigned short* WuzT = (unsigned short*)alloc((size_t)NHID * NIN * 2);
  unsigned short* WurT = (unsigned short*)alloc((size_t)NHID * NIN * 2);
  unsigned short* WuhT = (unsigned short*)alloc((size_t)NHID * NIN * 2);
  unsigned short* ub   = (unsigned short*)alloc((size_t)TSTEPS * NB * NIN * 2);
  unsigned short* hb   = (unsigned short*)alloc((size_t)NB * NHID * 2);
  unsigned short* sb   = (unsigned short*)alloc((size_t)NB * NHID * 2);
  unsigned* cntgen     = (unsigned*)alloc(256);

  float* out = (float*)d_out;
  float* hf  = out + NB * 10;   // h_final region of d_out

  int n1 = NHID * NHID;
  hipLaunchKernelGGL(k_transpose_bf16, dim3((n1 + 255) / 256), dim3(256), 0, stream, Whz, WhzT, NHID, NHID);
  hipLaunchKernelGGL(k_transpose_bf16, dim3((n1 + 255) / 256), dim3(256), 0, stream, Whr, WhrT, NHID, NHID);
  hipLaunchKernelGGL(k_transpose_bf16, dim3((n1 + 255) / 256), dim3(256), 0, stream, Whh, WhhT, NHID, NHID);
  int n2 = NIN * NHID;
  hipLaunchKernelGGL(k_transpose_bf16, dim3((n2 + 255) / 256), dim3(256), 0, stream, Wuz, WuzT, NIN, NHID);
  hipLaunchKernelGGL(k_transpose_bf16, dim3((n2 + 255) / 256), dim3(256), 0, stream, Wur, WurT, NIN, NHID);
  hipLaunchKernelGGL(k_transpose_bf16, dim3((n2 + 255) / 256), dim3(256), 0, stream, Wuh, WuhT, NIN, NHID);
  int n3 = TSTEPS * NB * NIN;
  hipLaunchKernelGGL(k_convert_bf16, dim3(2048), dim3(256), 0, stream, u, ub, n3);
  hipMemsetAsync(cntgen, 0, 8, stream);

  GruParams p;
  p.u = ub; p.WhzT = WhzT; p.WhrT = WhrT; p.WhhT = WhhT;
  p.WuzT = WuzT; p.WurT = WurT; p.WuhT = WuhT;
  p.bz = bz; p.br = br; p.bh = bh;
  p.h = hf; p.hb = hb; p.sb = sb;
  p.cnt = cntgen; p.gen = cntgen + 1;
  hipLaunchKernelGGL(gru_main, dim3(NBLK), dim3(NTHR), 0, stream, p);

  hipLaunchKernelGGL(k_logits, dim3(NB), dim3(64), 0, stream, hf, Why, by, out);
}

// Round 3
// 11065.421 us; speedup vs baseline: 3.6552x; 3.6552x over previous
//
#include <hip/hip_runtime.h>

#define NHID 1024
#define NB   128
#define NIN  64
#define TSTEPS 512
#define NBLK 128
#define NTHR 512

typedef __attribute__((ext_vector_type(8))) short short8v;
typedef __attribute__((ext_vector_type(4))) float f32x4;

__device__ __forceinline__ short8v ld8(const unsigned short* p) {
  return *reinterpret_cast<const short8v*>(p);
}

__device__ __forceinline__ unsigned short f2b(float x) {
  union { float f; unsigned u; } v; v.f = x;
  unsigned r = v.u + 0x7fffu + ((v.u >> 16) & 1u);
  return (unsigned short)(r >> 16);
}

// Coherence-point (bypass L1/L2) relaxed atomic ops — no cache fences needed.
__device__ __forceinline__ unsigned long long cload(const void* p) {
  return __hip_atomic_load((const unsigned long long*)p, __ATOMIC_RELAXED, __HIP_MEMORY_SCOPE_AGENT);
}
__device__ __forceinline__ void cstore16(unsigned short* p, unsigned short v) {
  __hip_atomic_store(p, v, __ATOMIC_RELAXED, __HIP_MEMORY_SCOPE_AGENT);
}

struct GruParams {
  const unsigned short* u;                    // [T][B][NIN] bf16
  const unsigned short* WhzT; const unsigned short* WhrT; const unsigned short* WhhT; // [n][k] bf16
  const unsigned short* WuzT; const unsigned short* WurT; const unsigned short* WuhT; // [n][k] bf16
  const float* bz; const float* br; const float* bh;
  float* h;                                   // [B][NHID] f32 (d_out region) — final only
  unsigned short* hb;                         // bf16 h broadcast buffer (coherent)
  unsigned short* sb;                         // bf16 r*h broadcast buffer (coherent)
  unsigned* cnt; unsigned* gen;
};

// Fence-free grid barrier: callers' coherent stores are drained (vmcnt) before
// arrival; cnt is monotonic (no reset race); pollers use relaxed bypass loads.
__device__ __forceinline__ void gridbar(unsigned* cnt, unsigned* gen, unsigned target) {
  asm volatile("s_waitcnt vmcnt(0)" ::: "memory");
  __syncthreads();   // all waves' stores drained before thread 0 arrives
  if (threadIdx.x == 0) {
    unsigned a = __hip_atomic_fetch_add(cnt, 1u, __ATOMIC_RELAXED, __HIP_MEMORY_SCOPE_AGENT);
    if (a == target * NBLK - 1u) {
      __hip_atomic_store(gen, target, __ATOMIC_RELAXED, __HIP_MEMORY_SCOPE_AGENT);
    } else {
      for (long long it = 0; it < (1ll << 22); ++it) {  // bounded: never hits unless bug
        if (__hip_atomic_load(gen, __ATOMIC_RELAXED, __HIP_MEMORY_SCOPE_AGENT) >= target) break;
        __builtin_amdgcn_s_sleep(1);
      }
    }
  }
  __syncthreads();
}

// Block = 16 batch rows (rg) x 64 hidden cols (cg). 8 waves: ct = col-tile (4 x 16
// cols), kh = K-half (2 x 512). A-fragments staged to LDS once per phase.
__global__ __launch_bounds__(NTHR, 1) void gru_main(GruParams p) {
  __shared__ unsigned short stage[16 * NHID];   // 32KB staged h/s rows (swizzled)
  __shared__ float red[2][4][64][4];            // K-half reduction, 8KB

  const int tid  = threadIdx.x;
  const int lane = tid & 63;
  const int w    = tid >> 6;
  const int ct   = w & 3;
  const int kh   = w >> 2;
  const int rg   = blockIdx.x >> 4;   // 8 row groups
  const int cg   = blockIdx.x & 15;   // 16 col groups
  const int lr   = lane & 15;
  const int lk   = (lane >> 4) * 8;

  const int colN = cg * 64 + ct * 16 + lr;      // B-frag col / output col
  const unsigned short* wz  = p.WhzT + (size_t)colN * NHID + kh * 512 + lk;
  const unsigned short* wr  = p.WhrT + (size_t)colN * NHID + kh * 512 + lk;
  const unsigned short* wh  = p.WhhT + (size_t)colN * NHID + kh * 512 + lk;
  const unsigned short* wuz = p.WuzT + colN * NIN + lk;
  const unsigned short* wur = p.WurT + colN * NIN + lk;
  const unsigned short* wuh = p.WuhT + colN * NIN + lk;

  const int orow0 = (lane >> 4) * 4;            // block-local output row base
  const float bzv = p.bz[colN];
  const float brv = p.br[colN];
  const float bhv = p.bh[colN];

  const unsigned short* hbR = p.hb + (size_t)rg * 16 * NHID;  // block's row slice
  const unsigned short* sbR = p.sb + (size_t)rg * 16 * NHID;

  float h_own[4] = {0.f, 0.f, 0.f, 0.f};
  float zreg[4];

  // Stage 16 rows x 1024 cols bf16 (= 2048 16B units) from a coherent buffer
  // into swizzled LDS. 512 threads x 4 iters = 2048 units.
#define STAGE(SRC)                                                              \
  {                                                                             \
    _Pragma("unroll")                                                           \
    for (int s = 0; s < 4; ++s) {                                               \
      int j   = tid + s * NTHR;      /* 16B unit id 0..2047 */                  \
      int row = j >> 7;                                                         \
      int kc  = j & 127;                                                        \
      const unsigned short* g = (SRC) + row * NHID + kc * 8;                    \
      unsigned long long lo = cload(g);                                         \
      unsigned long long hi = cload(g + 4);                                     \
      char* d = (char*)stage + ((row * 2048) | ((kc * 16) ^ ((row & 7) << 4))); \
      *(unsigned long long*)d = lo;                                             \
      *((unsigned long long*)d + 1) = hi;                                       \
    }                                                                           \
  }

#define LDSA(IT)                                                                \
  (*(const short8v*)((const char*)stage +                                       \
     ((lr * 2048) | ((((kh * 512 + (IT) * 32 + lk) * 2)) ^ ((lr & 7) << 4)))))

  for (int t = 0; t < TSTEPS; ++t) {
    // ======== phase A: z, r ========
    STAGE(hbR);
    __syncthreads();

    f32x4 az = {0.f, 0.f, 0.f, 0.f};
    f32x4 ar = {0.f, 0.f, 0.f, 0.f};
#pragma unroll 4
    for (int it = 0; it < 16; ++it) {
      short8v a = LDSA(it);
      az = __builtin_amdgcn_mfma_f32_16x16x32_bf16(a, ld8(wz + it * 32), az, 0, 0, 0);
      ar = __builtin_amdgcn_mfma_f32_16x16x32_bf16(a, ld8(wr + it * 32), ar, 0, 0, 0);
    }
    if (kh) {
      const unsigned short* au = p.u + ((size_t)t * NB + rg * 16 + lr) * NIN + lk;
#pragma unroll
      for (int it = 0; it < 2; ++it) {
        short8v a = ld8(au + it * 32);
        az = __builtin_amdgcn_mfma_f32_16x16x32_bf16(a, ld8(wuz + it * 32), az, 0, 0, 0);
        ar = __builtin_amdgcn_mfma_f32_16x16x32_bf16(a, ld8(wur + it * 32), ar, 0, 0, 0);
      }
      *(f32x4*)&red[0][ct][lane][0] = az;
      *(f32x4*)&red[1][ct][lane][0] = ar;
    }
    __syncthreads();
    if (!kh) {
      az += *(const f32x4*)&red[0][ct][lane][0];
      ar += *(const f32x4*)&red[1][ct][lane][0];
#pragma unroll
      for (int i = 0; i < 4; ++i) {
        float z = 1.f / (1.f + __expf(-(az[i] + bzv)));
        float r = 1.f / (1.f + __expf(-(ar[i] + brv)));
        zreg[i] = z;
        cstore16(p.sb + (size_t)(rg * 16 + orow0 + i) * NHID + colN, f2b(r * h_own[i]));
      }
    }
    gridbar(p.cnt, p.gen, 2 * t + 1);

    // ======== phase B: h_tilde, h ========
    STAGE(sbR);
    __syncthreads();

    f32x4 ac = {0.f, 0.f, 0.f, 0.f};
#pragma unroll 4
    for (int it = 0; it < 16; ++it) {
      ac = __builtin_amdgcn_mfma_f32_16x16x32_bf16(LDSA(it), ld8(wh + it * 32), ac, 0, 0, 0);
    }
    if (kh) {
      const unsigned short* au = p.u + ((size_t)t * NB + rg * 16 + lr) * NIN + lk;
#pragma unroll
      for (int it = 0; it < 2; ++it) {
        ac = __builtin_amdgcn_mfma_f32_16x16x32_bf16(ld8(au + it * 32), ld8(wuh + it * 32), ac, 0, 0, 0);
      }
      *(f32x4*)&red[0][ct][lane][0] = ac;
    }
    __syncthreads();
    if (!kh) {
      ac += *(const f32x4*)&red[0][ct][lane][0];
#pragma unroll
      for (int i = 0; i < 4; ++i) {
        float x = ac[i] + bhv;
        float e = __expf(2.f * x);
        float ht = 1.f - 2.f / (e + 1.f);          // tanh, overflow-safe
        float hn = (1.f - zreg[i]) * h_own[i] + zreg[i] * ht;
        h_own[i] = hn;
        cstore16(p.hb + (size_t)(rg * 16 + orow0 + i) * NHID + colN, f2b(hn));
      }
      if (t == TSTEPS - 1) {
#pragma unroll
        for (int i = 0; i < 4; ++i)
          p.h[(size_t)(rg * 16 + orow0 + i) * NHID + colN] = h_own[i];
      }
    }
    gridbar(p.cnt, p.gen, 2 * t + 2);
  }
#undef STAGE
#undef LDSA
}

// out[c*R + r] = bf16(in[r*C + c])  (W[k][n] -> WT[n][k])
__global__ void k_transpose_bf16(const float* in, unsigned short* out, int R, int C) {
  int idx = blockIdx.x * 256 + threadIdx.x;
  if (idx < R * C) {
    int r = idx / C, c = idx % C;
    out[(size_t)c * R + r] = f2b(in[idx]);
  }
}

__global__ void k_convert_bf16(const float* in, unsigned short* out, int n) {
  for (int i = blockIdx.x * 256 + threadIdx.x; i < n; i += gridDim.x * 256)
    out[i] = f2b(in[i]);
}

// logits = h_final @ W_hy + b_y ; one block (64 lanes) per batch row
__global__ void k_logits(const float* __restrict__ h, const float* __restrict__ Why,
                         const float* __restrict__ by, float* __restrict__ out) {
  int row = blockIdx.x;
  int lane = threadIdx.x;
  float acc[10];
#pragma unroll
  for (int j = 0; j < 10; ++j) acc[j] = 0.f;
  for (int k = lane; k < NHID; k += 64) {
    float hv = h[row * NHID + k];
#pragma unroll
    for (int j = 0; j < 10; ++j) acc[j] += hv * Why[k * 10 + j];
  }
#pragma unroll
  for (int j = 0; j < 10; ++j)
    for (int off = 32; off; off >>= 1) acc[j] += __shfl_down(acc[j], off);
  if (lane == 0) {
#pragma unroll
    for (int j = 0; j < 10; ++j) out[row * 10 + j] = acc[j] + by[j];
  }
}

extern "C" void kernel_launch(void* const* d_in, const int* in_sizes, int n_in,
                              void* d_out, int out_size, void* d_ws, size_t ws_size,
                              hipStream_t stream) {
  (void)in_sizes; (void)n_in; (void)out_size; (void)ws_size;
  const float* u   = (const float*)d_in[0];
  const float* Wuz = (const float*)d_in[1];
  const float* Whz = (const float*)d_in[2];
  const float* bz  = (const float*)d_in[3];
  const float* Wur = (const float*)d_in[4];
  const float* Whr = (const float*)d_in[5];
  const float* br  = (const float*)d_in[6];
  const float* Wuh = (const float*)d_in[7];
  const float* Whh = (const float*)d_in[8];
  const float* bh  = (const float*)d_in[9];
  const float* Why = (const float*)d_in[10];
  const float* by  = (const float*)d_in[11];

  char* ws = (char*)d_ws;
  size_t off = 0;
  auto alloc = [&](size_t bytes) { char* p = ws + off; off += (bytes + 255) & ~255ull; return p; };
  unsigned short* WhzT = (unsigned short*)alloc((size_t)NHID * NHID * 2);
  unsigned short* WhrT = (unsigned short*)alloc((size_t)NHID * NHID * 2);
  unsigned short* WhhT = (unsigned short*)alloc((size_t)NHID * NHID * 2);
  unsigned short* WuzT = (unsigned short*)alloc((size_t)NHID * NIN * 2);
  unsigned short* WurT = (unsigned short*)alloc((size_t)NHID * NIN * 2);
  unsigned short* WuhT = (unsigned short*)alloc((size_t)NHID * NIN * 2);
  unsigned short* ub   = (unsigned short*)alloc((size_t)TSTEPS * NB * NIN * 2);
  unsigned short* hb   = (unsigned short*)alloc((size_t)NB * NHID * 2);
  unsigned short* sb   = (unsigned short*)alloc((size_t)NB * NHID * 2);
  unsigned* cntgen     = (unsigned*)alloc(256);

  float* out = (float*)d_out;
  float* hf  = out + NB * 10;   // h_final region of d_out

  int n1 = NHID * NHID;
  hipLaunchKernelGGL(k_transpose_bf16, dim3((n1 + 255) / 256), dim3(256), 0, stream, Whz, WhzT, NHID, NHID);
  hipLaunchKernelGGL(k_transpose_bf16, dim3((n1 + 255) / 256), dim3(256), 0, stream, Whr, WhrT, NHID, NHID);
  hipLaunchKernelGGL(k_transpose_bf16, dim3((n1 + 255) / 256), dim3(256), 0, stream, Whh, WhhT, NHID, NHID);
  int n2 = NIN * NHID;
  hipLaunchKernelGGL(k_transpose_bf16, dim3((n2 + 255) / 256), dim3(256), 0, stream, Wuz, WuzT, NIN, NHID);
  hipLaunchKernelGGL(k_transpose_bf16, dim3((n2 + 255) / 256), dim3(256), 0, stream, Wur, WurT, NIN, NHID);
  hipLaunchKernelGGL(k_transpose_bf16, dim3((n2 + 255) / 256), dim3(256), 0, stream, Wuh, WuhT, NIN, NHID);
  int n3 = TSTEPS * NB * NIN;
  hipLaunchKernelGGL(k_convert_bf16, dim3(2048), dim3(256), 0, stream, u, ub, n3);
  // h0 = 0 broadcast buffer + barrier state (kernel-boundary flush makes these
  // visible to the coherent bypass loads in gru_main)
  hipMemsetAsync(hb, 0, (size_t)NB * NHID * 2, stream);
  hipMemsetAsync(cntgen, 0, 8, stream);

  GruParams p;
  p.u = ub; p.WhzT = WhzT; p.WhrT = WhrT; p.WhhT = WhhT;
  p.WuzT = WuzT; p.WurT = WurT; p.WuhT = WuhT;
  p.bz = bz; p.br = br; p.bh = bh;
  p.h = hf; p.hb = hb; p.sb = sb;
  p.cnt = cntgen; p.gen = cntgen + 1;
  hipLaunchKernelGGL(gru_main, dim3(NBLK), dim3(NTHR), 0, stream, p);

  hipLaunchKernelGGL(k_logits, dim3(NB), dim3(64), 0, stream, hf, Why, by, out);
}

// Round 4
// 9552.619 us; speedup vs baseline: 4.2341x; 1.1584x over previous
//
#include <hip/hip_runtime.h>

#define NHID 1024
#define NB   128
#define NIN  64
#define TSTEPS 512
#define NBLK 128
#define NTHR 512

typedef __attribute__((ext_vector_type(8))) short short8v;
typedef __attribute__((ext_vector_type(4))) float f32x4;

__device__ __forceinline__ short8v ld8(const unsigned short* p) {
  return *reinterpret_cast<const short8v*>(p);
}

__device__ __forceinline__ unsigned short f2b(float x) {
  union { float f; unsigned u; } v; v.f = x;
  unsigned r = v.u + 0x7fffu + ((v.u >> 16) & 1u);
  return (unsigned short)(r >> 16);
}

// Coherence-point (bypass L1/L2) relaxed atomics — no cache-maintenance fences.
__device__ __forceinline__ unsigned long long cload(const void* p) {
  return __hip_atomic_load((const unsigned long long*)p, __ATOMIC_RELAXED, __HIP_MEMORY_SCOPE_AGENT);
}
__device__ __forceinline__ unsigned cload32(const unsigned* p) {
  return __hip_atomic_load(p, __ATOMIC_RELAXED, __HIP_MEMORY_SCOPE_AGENT);
}
__device__ __forceinline__ void cstore16(unsigned short* p, unsigned short v) {
  __hip_atomic_store(p, v, __ATOMIC_RELAXED, __HIP_MEMORY_SCOPE_AGENT);
}
__device__ __forceinline__ void cstore32(unsigned* p, unsigned v) {
  __hip_atomic_store(p, v, __ATOMIC_RELAXED, __HIP_MEMORY_SCOPE_AGENT);
}

struct GruParams {
  const unsigned short* u;                    // [T][B][NIN] bf16
  const unsigned short* WhzT; const unsigned short* WhrT; const unsigned short* WhhT; // [n][k]
  const unsigned short* WuzT; const unsigned short* WurT; const unsigned short* WuhT; // [n][k]
  const float* bz; const float* br; const float* bh;
  float* h;                                   // [B][NHID] f32 — final h only
  unsigned short* hb;                         // bf16 h broadcast (coherent)
  unsigned short* sb;                         // bf16 r*h broadcast (coherent)
  unsigned* flags;                            // [8 groups][64 u32] phase flags
};

// Group barrier, wait side: wave 0's lanes 0..15 each watch one block's flag.
// No atomics, no release hop — each poller independently observes all flags.
__device__ __forceinline__ void group_wait(const unsigned* gflags, int lane, int w, unsigned pc) {
  if (w == 0) {
    const bool mine = lane < 16;
    const unsigned* fp = gflags + (mine ? lane : 0);
    for (int spin = 0; spin < (1 << 20); ++spin) {   // bounded: only hits on a real bug
      unsigned v = cload32(fp);
      if (__all((!mine) | (v >= pc))) break;
    }
  }
  __syncthreads();
}

// Block = 16 batch rows (rg) x 64 hidden cols (cg). 8 waves: ct = col-tile, kh = K-half.
// All h/s exchange stays within the 16 blocks sharing rg -> per-group barriers.
__global__ __launch_bounds__(NTHR, 2) void gru_main(GruParams p) {
  __shared__ unsigned short stage[16 * NHID];   // 32KB staged h/s rows (swizzled)
  __shared__ float red[2][4][4][64];            // K-half reduction, component-major

  const int tid  = threadIdx.x;
  const int lane = tid & 63;
  const int w    = tid >> 6;
  const int ct   = w & 3;
  const int kh   = w >> 2;
  const int rg   = blockIdx.x >> 4;   // 8 row groups
  const int cg   = blockIdx.x & 15;   // 16 col groups
  const int lr   = lane & 15;
  const int lk   = (lane >> 4) * 8;

  const int colN = cg * 64 + ct * 16 + lr;
  const unsigned short* wz  = p.WhzT + (size_t)colN * NHID + kh * 512 + lk;
  const unsigned short* wr  = p.WhrT + (size_t)colN * NHID + kh * 512 + lk;
  const unsigned short* wh  = p.WhhT + (size_t)colN * NHID + kh * 512 + lk;
  const unsigned short* wuz = p.WuzT + colN * NIN + lk;
  const unsigned short* wur = p.WurT + colN * NIN + lk;
  const unsigned short* wuh = p.WuhT + colN * NIN + lk;

  const int orow0 = (lane >> 4) * 4;
  const float bzv = p.bz[colN];
  const float brv = p.br[colN];
  const float bhv = p.bh[colN];

  const unsigned short* hbR = p.hb + (size_t)rg * 16 * NHID;
  const unsigned short* sbR = p.sb + (size_t)rg * 16 * NHID;
  unsigned* gflags = p.flags + rg * 64;
  unsigned* myflag = gflags + cg;

  // Loop-invariant recurrent-weight B-fragments -> VGPRs (48 x 16B = 192 regs).
  short8v Wz[16], Wr[16], Wh[16];
#pragma unroll
  for (int it = 0; it < 16; ++it) {
    Wz[it] = ld8(wz + it * 32);
    Wr[it] = ld8(wr + it * 32);
    Wh[it] = ld8(wh + it * 32);
  }

  float h_own[4] = {0.f, 0.f, 0.f, 0.f};
  float zreg[4];

  // Stage 16 rows x 1024 cols bf16 (2048 16B units; 512 thr x 4) into swizzled LDS.
#define STAGE(SRC)                                                              \
  {                                                                             \
    _Pragma("unroll")                                                           \
    for (int s = 0; s < 4; ++s) {                                               \
      int j   = tid + s * NTHR;                                                 \
      int row = j >> 7;                                                         \
      int kc  = j & 127;                                                        \
      const unsigned short* g = (SRC) + row * NHID + kc * 8;                    \
      unsigned long long lo = cload(g);                                         \
      unsigned long long hi = cload(g + 4);                                     \
      char* d = (char*)stage + ((row * 2048) | ((kc * 16) ^ ((row & 7) << 4))); \
      *(unsigned long long*)d = lo;                                             \
      *((unsigned long long*)d + 1) = hi;                                       \
    }                                                                           \
  }

#define LDSA(IT)                                                                \
  (*(const short8v*)((const char*)stage +                                       \
     ((lr * 2048) | ((((kh * 512 + (IT) * 32 + lk) * 2)) ^ ((lr & 7) << 4)))))

  for (int t = 0; t < TSTEPS; ++t) {
    const unsigned short* au = p.u + ((size_t)t * NB + rg * 16 + lr) * NIN + lk;

    // ======== phase A: z, r ========
    f32x4 az = {0.f, 0.f, 0.f, 0.f};
    f32x4 ar = {0.f, 0.f, 0.f, 0.f};
    if (kh) {        // u-projection overlaps the group wait
#pragma unroll
      for (int it = 0; it < 2; ++it) {
        short8v a = ld8(au + it * 32);
        az = __builtin_amdgcn_mfma_f32_16x16x32_bf16(a, ld8(wuz + it * 32), az, 0, 0, 0);
        ar = __builtin_amdgcn_mfma_f32_16x16x32_bf16(a, ld8(wur + it * 32), ar, 0, 0, 0);
      }
    }
    group_wait(gflags, lane, w, 2 * t);      // h(t) ready (t=0: trivially)
    STAGE(hbR);
    __syncthreads();

#pragma unroll 4
    for (int it = 0; it < 16; ++it) {
      short8v a = LDSA(it);
      az = __builtin_amdgcn_mfma_f32_16x16x32_bf16(a, Wz[it], az, 0, 0, 0);
      ar = __builtin_amdgcn_mfma_f32_16x16x32_bf16(a, Wr[it], ar, 0, 0, 0);
    }
    if (kh) {
#pragma unroll
      for (int j = 0; j < 4; ++j) { red[0][ct][j][lane] = az[j]; red[1][ct][j][lane] = ar[j]; }
    }
    __syncthreads();
    if (!kh) {
#pragma unroll
      for (int i = 0; i < 4; ++i) {
        float z = 1.f / (1.f + __expf(-(az[i] + red[0][ct][i][lane] + bzv)));
        float r = 1.f / (1.f + __expf(-(ar[i] + red[1][ct][i][lane] + brv)));
        zreg[i] = z;
        cstore16(p.sb + (size_t)(rg * 16 + orow0 + i) * NHID + colN, f2b(r * h_own[i]));
      }
    }
    asm volatile("s_waitcnt vmcnt(0)" ::: "memory");
    __syncthreads();
    if (tid == 0) cstore32(myflag, 2 * t + 1);

    // ======== phase B: h_tilde, h ========
    f32x4 ac = {0.f, 0.f, 0.f, 0.f};
    if (kh) {
#pragma unroll
      for (int it = 0; it < 2; ++it) {
        ac = __builtin_amdgcn_mfma_f32_16x16x32_bf16(ld8(au + it * 32), ld8(wuh + it * 32), ac, 0, 0, 0);
      }
    }
    group_wait(gflags, lane, w, 2 * t + 1);  // s(t) ready
    STAGE(sbR);
    __syncthreads();

#pragma unroll 4
    for (int it = 0; it < 16; ++it) {
      ac = __builtin_amdgcn_mfma_f32_16x16x32_bf16(LDSA(it), Wh[it], ac, 0, 0, 0);
    }
    if (kh) {
#pragma unroll
      for (int j = 0; j < 4; ++j) red[0][ct][j][lane] = ac[j];
    }
    __syncthreads();
    if (!kh) {
#pragma unroll
      for (int i = 0; i < 4; ++i) {
        float x = ac[i] + red[0][ct][i][lane] + bhv;
        float e = __expf(2.f * x);
        float ht = 1.f - 2.f / (e + 1.f);          // tanh, overflow-safe
        float hn = (1.f - zreg[i]) * h_own[i] + zreg[i] * ht;
        h_own[i] = hn;
        cstore16(p.hb + (size_t)(rg * 16 + orow0 + i) * NHID + colN, f2b(hn));
      }
      if (t == TSTEPS - 1) {
#pragma unroll
        for (int i = 0; i < 4; ++i)
          p.h[(size_t)(rg * 16 + orow0 + i) * NHID + colN] = h_own[i];
      }
    }
    asm volatile("s_waitcnt vmcnt(0)" ::: "memory");
    __syncthreads();
    if (tid == 0) cstore32(myflag, 2 * t + 2);
  }
#undef STAGE
#undef LDSA
}

// out[c*R + r] = bf16(in[r*C + c])  (W[k][n] -> WT[n][k])
__global__ void k_transpose_bf16(const float* in, unsigned short* out, int R, int C) {
  int idx = blockIdx.x * 256 + threadIdx.x;
  if (idx < R * C) {
    int r = idx / C, c = idx % C;
    out[(size_t)c * R + r] = f2b(in[idx]);
  }
}

__global__ void k_convert_bf16(const float* in, unsigned short* out, int n) {
  for (int i = blockIdx.x * 256 + threadIdx.x; i < n; i += gridDim.x * 256)
    out[i] = f2b(in[i]);
}

// logits = h_final @ W_hy + b_y ; one block (64 lanes) per batch row
__global__ void k_logits(const float* __restrict__ h, const float* __restrict__ Why,
                         const float* __restrict__ by, float* __restrict__ out) {
  int row = blockIdx.x;
  int lane = threadIdx.x;
  float acc[10];
#pragma unroll
  for (int j = 0; j < 10; ++j) acc[j] = 0.f;
  for (int k = lane; k < NHID; k += 64) {
    float hv = h[row * NHID + k];
#pragma unroll
    for (int j = 0; j < 10; ++j) acc[j] += hv * Why[k * 10 + j];
  }
#pragma unroll
  for (int j = 0; j < 10; ++j)
    for (int off = 32; off; off >>= 1) acc[j] += __shfl_down(acc[j], off);
  if (lane == 0) {
#pragma unroll
    for (int j = 0; j < 10; ++j) out[row * 10 + j] = acc[j] + by[j];
  }
}

extern "C" void kernel_launch(void* const* d_in, const int* in_sizes, int n_in,
                              void* d_out, int out_size, void* d_ws, size_t ws_size,
                              hipStream_t stream) {
  (void)in_sizes; (void)n_in; (void)out_size; (void)ws_size;
  const float* u   = (const float*)d_in[0];
  const float* Wuz = (const float*)d_in[1];
  const float* Whz = (const float*)d_in[2];
  const float* bz  = (const float*)d_in[3];
  const float* Wur = (const float*)d_in[4];
  const float* Whr = (const float*)d_in[5];
  const float* br  = (const float*)d_in[6];
  const float* Wuh = (const float*)d_in[7];
  const float* Whh = (const float*)d_in[8];
  const float* bh  = (const float*)d_in[9];
  const float* Why = (const float*)d_in[10];
  const float* by  = (const float*)d_in[11];

  char* ws = (char*)d_ws;
  size_t off = 0;
  auto alloc = [&](size_t bytes) { char* p = ws + off; off += (bytes + 255) & ~255ull; return p; };
  unsigned short* WhzT = (unsigned short*)alloc((size_t)NHID * NHID * 2);
  unsigned short* WhrT = (unsigned short*)alloc((size_t)NHID * NHID * 2);
  unsigned short* WhhT = (unsigned short*)alloc((size_t)NHID * NHID * 2);
  unsigned short* WuzT = (unsigned short*)alloc((size_t)NHID * NIN * 2);
  unsigned short* WurT = (unsigned short*)alloc((size_t)NHID * NIN * 2);
  unsigned short* WuhT = (unsigned short*)alloc((size_t)NHID * NIN * 2);
  unsigned short* ub   = (unsigned short*)alloc((size_t)TSTEPS * NB * NIN * 2);
  unsigned short* hb   = (unsigned short*)alloc((size_t)NB * NHID * 2);
  unsigned short* sb   = (unsigned short*)alloc((size_t)NB * NHID * 2);
  unsigned* flags      = (unsigned*)alloc(4096);

  float* out = (float*)d_out;
  float* hf  = out + NB * 10;   // h_final region of d_out

  int n1 = NHID * NHID;
  hipLaunchKernelGGL(k_transpose_bf16, dim3((n1 + 255) / 256), dim3(256), 0, stream, Whz, WhzT, NHID, NHID);
  hipLaunchKernelGGL(k_transpose_bf16, dim3((n1 + 255) / 256), dim3(256), 0, stream, Whr, WhrT, NHID, NHID);
  hipLaunchKernelGGL(k_transpose_bf16, dim3((n1 + 255) / 256), dim3(256), 0, stream, Whh, WhhT, NHID, NHID);
  int n2 = NIN * NHID;
  hipLaunchKernelGGL(k_transpose_bf16, dim3((n2 + 255) / 256), dim3(256), 0, stream, Wuz, WuzT, NIN, NHID);
  hipLaunchKernelGGL(k_transpose_bf16, dim3((n2 + 255) / 256), dim3(256), 0, stream, Wur, WurT, NIN, NHID);
  hipLaunchKernelGGL(k_transpose_bf16, dim3((n2 + 255) / 256), dim3(256), 0, stream, Wuh, WuhT, NIN, NHID);
  int n3 = TSTEPS * NB * NIN;
  hipLaunchKernelGGL(k_convert_bf16, dim3(2048), dim3(256), 0, stream, u, ub, n3);
  hipMemsetAsync(hb, 0, (size_t)NB * NHID * 2, stream);   // h0 = 0
  hipMemsetAsync(flags, 0, 4096, stream);

  GruParams p;
  p.u = ub; p.WhzT = WhzT; p.WhrT = WhrT; p.WhhT = WhhT;
  p.WuzT = WuzT; p.WurT = WurT; p.WuhT = WuhT;
  p.bz = bz; p.br = br; p.bh = bh;
  p.h = hf; p.hb = hb; p.sb = sb;
  p.flags = flags;
  hipLaunchKernelGGL(gru_main, dim3(NBLK), dim3(NTHR), 0, stream, p);

  hipLaunchKernelGGL(k_logits, dim3(NB), dim3(64), 0, stream, hf, Why, by, out);
}

// Round 5
// 5847.092 us; speedup vs baseline: 6.9174x; 1.6337x over previous
//
#include <hip/hip_runtime.h>

#define NHID 1024
#define NB   128
#define NIN  64
#define TSTEPS 512
#define NBLK 128
#define NTHR 512

typedef __attribute__((ext_vector_type(8))) short short8v;
typedef __attribute__((ext_vector_type(4))) float f32x4;

__device__ __forceinline__ short8v ld8(const unsigned short* p) {
  return *reinterpret_cast<const short8v*>(p);
}

__device__ __forceinline__ unsigned short f2b(float x) {
  union { float f; unsigned u; } v; v.f = x;
  unsigned r = v.u + 0x7fffu + ((v.u >> 16) & 1u);
  return (unsigned short)(r >> 16);
}

// Coherence-point (bypass L1/L2) relaxed atomics — no cache-maintenance fences.
__device__ __forceinline__ unsigned long long cload(const void* p) {
  return __hip_atomic_load((const unsigned long long*)p, __ATOMIC_RELAXED, __HIP_MEMORY_SCOPE_AGENT);
}
__device__ __forceinline__ unsigned cload32(const unsigned* p) {
  return __hip_atomic_load(p, __ATOMIC_RELAXED, __HIP_MEMORY_SCOPE_AGENT);
}
__device__ __forceinline__ void cstore16(unsigned short* p, unsigned short v) {
  __hip_atomic_store(p, v, __ATOMIC_RELAXED, __HIP_MEMORY_SCOPE_AGENT);
}
__device__ __forceinline__ void cstore32(unsigned* p, unsigned v) {
  __hip_atomic_store(p, v, __ATOMIC_RELAXED, __HIP_MEMORY_SCOPE_AGENT);
}

struct GruParams {
  const unsigned short* u;                    // [T][B][NIN] bf16
  const unsigned short* WhzT; const unsigned short* WhrT; const unsigned short* WhhT; // [n][k]
  const unsigned short* WuzT; const unsigned short* WurT; const unsigned short* WuhT; // [n][k]
  const float* bz; const float* br; const float* bh;
  float* h;                                   // [B][NHID] f32 — final h only
  unsigned short* hb;                         // bf16 h broadcast (coherent)
  unsigned short* sb;                         // bf16 r*h broadcast (coherent)
  unsigned* flags;                            // [8 groups][64 u32] phase flags
};

// Group barrier, wait side: wave 0's lanes 0..15 each watch one block's flag.
// No atomics, no release hop — each poller independently observes all flags.
__device__ __forceinline__ void group_wait(const unsigned* gflags, int lane, int w, unsigned pc) {
  if (w == 0) {
    const bool mine = lane < 16;
    const unsigned* fp = gflags + (mine ? lane : 0);
    for (int spin = 0; spin < (1 << 20); ++spin) {   // bounded: only hits on a real bug
      unsigned v = cload32(fp);
      if (__all((!mine) | (v >= pc))) break;
    }
  }
  __syncthreads();
}

// Block = 16 batch rows (rg) x 64 hidden cols (cg). 8 waves: ct = col-tile, kh = K-half.
// All h/s exchange stays within the 16 blocks sharing rg -> per-group barriers.
__global__ __launch_bounds__(NTHR, 2) void gru_main(GruParams p) {
  __shared__ unsigned short stage[16 * NHID];   // 32KB staged h/s rows (swizzled)
  __shared__ float red[2][4][4][64];            // K-half reduction, component-major

  const int tid  = threadIdx.x;
  const int lane = tid & 63;
  const int w    = tid >> 6;
  const int ct   = w & 3;
  const int kh   = w >> 2;
  const int rg   = blockIdx.x >> 4;   // 8 row groups
  const int cg   = blockIdx.x & 15;   // 16 col groups
  const int lr   = lane & 15;
  const int lk   = (lane >> 4) * 8;

  const int colN = cg * 64 + ct * 16 + lr;
  const unsigned short* wz  = p.WhzT + (size_t)colN * NHID + kh * 512 + lk;
  const unsigned short* wr  = p.WhrT + (size_t)colN * NHID + kh * 512 + lk;
  const unsigned short* wh  = p.WhhT + (size_t)colN * NHID + kh * 512 + lk;
  const unsigned short* wuz = p.WuzT + colN * NIN + lk;
  const unsigned short* wur = p.WurT + colN * NIN + lk;
  const unsigned short* wuh = p.WuhT + colN * NIN + lk;

  const int orow0 = (lane >> 4) * 4;
  const float bzv = p.bz[colN];
  const float brv = p.br[colN];
  const float bhv = p.bh[colN];

  const unsigned short* hbR = p.hb + (size_t)rg * 16 * NHID;
  const unsigned short* sbR = p.sb + (size_t)rg * 16 * NHID;
  unsigned* gflags = p.flags + rg * 64;
  unsigned* myflag = gflags + cg;

  // Loop-invariant recurrent-weight B-fragments -> VGPRs (48 x 16B = 192 regs).
  // NOTE: every use below is in a FULLY unrolled loop (static indices) — a
  // partial unroll would demote these arrays to scratch (rule #20).
  short8v Wz[16], Wr[16], Wh[16];
#pragma unroll
  for (int it = 0; it < 16; ++it) {
    Wz[it] = ld8(wz + it * 32);
    Wr[it] = ld8(wr + it * 32);
    Wh[it] = ld8(wh + it * 32);
  }

  float h_own[4] = {0.f, 0.f, 0.f, 0.f};
  float zreg[4];

  // Stage 16 rows x 1024 cols bf16 (2048 16B units; 512 thr x 4) into swizzled LDS.
#define STAGE(SRC)                                                              \
  {                                                                             \
    _Pragma("unroll")                                                           \
    for (int s = 0; s < 4; ++s) {                                               \
      int j   = tid + s * NTHR;                                                 \
      int row = j >> 7;                                                         \
      int kc  = j & 127;                                                        \
      const unsigned short* g = (SRC) + row * NHID + kc * 8;                    \
      unsigned long long lo = cload(g);                                         \
      unsigned long long hi = cload(g + 4);                                     \
      char* d = (char*)stage + ((row * 2048) | ((kc * 16) ^ ((row & 7) << 4))); \
      *(unsigned long long*)d = lo;                                             \
      *((unsigned long long*)d + 1) = hi;                                       \
    }                                                                           \
  }

#define LDSA(IT)                                                                \
  (*(const short8v*)((const char*)stage +                                       \
     ((lr * 2048) | ((((kh * 512 + (IT) * 32 + lk) * 2)) ^ ((lr & 7) << 4)))))

  for (int t = 0; t < TSTEPS; ++t) {
    const unsigned short* au = p.u + ((size_t)t * NB + rg * 16 + lr) * NIN + lk;

    // ======== phase A: z, r ========
    f32x4 az = {0.f, 0.f, 0.f, 0.f};
    f32x4 ar = {0.f, 0.f, 0.f, 0.f};
    if (kh) {        // u-projection overlaps the group wait
#pragma unroll
      for (int it = 0; it < 2; ++it) {
        short8v a = ld8(au + it * 32);
        az = __builtin_amdgcn_mfma_f32_16x16x32_bf16(a, ld8(wuz + it * 32), az, 0, 0, 0);
        ar = __builtin_amdgcn_mfma_f32_16x16x32_bf16(a, ld8(wur + it * 32), ar, 0, 0, 0);
      }
    }
    group_wait(gflags, lane, w, 2 * t);      // h(t) ready (t=0: trivially)
    STAGE(hbR);
    __syncthreads();

#pragma unroll
    for (int it = 0; it < 16; ++it) {
      short8v a = LDSA(it);
      az = __builtin_amdgcn_mfma_f32_16x16x32_bf16(a, Wz[it], az, 0, 0, 0);
      ar = __builtin_amdgcn_mfma_f32_16x16x32_bf16(a, Wr[it], ar, 0, 0, 0);
    }
    if (kh) {
#pragma unroll
      for (int j = 0; j < 4; ++j) { red[0][ct][j][lane] = az[j]; red[1][ct][j][lane] = ar[j]; }
    }
    __syncthreads();
    if (!kh) {
#pragma unroll
      for (int i = 0; i < 4; ++i) {
        float z = 1.f / (1.f + __expf(-(az[i] + red[0][ct][i][lane] + bzv)));
        float r = 1.f / (1.f + __expf(-(ar[i] + red[1][ct][i][lane] + brv)));
        zreg[i] = z;
        cstore16(p.sb + (size_t)(rg * 16 + orow0 + i) * NHID + colN, f2b(r * h_own[i]));
      }
    }
    asm volatile("s_waitcnt vmcnt(0)" ::: "memory");
    __syncthreads();
    if (tid == 0) cstore32(myflag, 2 * t + 1);

    // ======== phase B: h_tilde, h ========
    f32x4 ac = {0.f, 0.f, 0.f, 0.f};
    if (kh) {
#pragma unroll
      for (int it = 0; it < 2; ++it) {
        ac = __builtin_amdgcn_mfma_f32_16x16x32_bf16(ld8(au + it * 32), ld8(wuh + it * 32), ac, 0, 0, 0);
      }
    }
    group_wait(gflags, lane, w, 2 * t + 1);  // s(t) ready
    STAGE(sbR);
    __syncthreads();

#pragma unroll
    for (int it = 0; it < 16; ++it) {
      ac = __builtin_amdgcn_mfma_f32_16x16x32_bf16(LDSA(it), Wh[it], ac, 0, 0, 0);
    }
    if (kh) {
#pragma unroll
      for (int j = 0; j < 4; ++j) red[0][ct][j][lane] = ac[j];
    }
    __syncthreads();
    if (!kh) {
#pragma unroll
      for (int i = 0; i < 4; ++i) {
        float x = ac[i] + red[0][ct][i][lane] + bhv;
        float e = __expf(2.f * x);
        float ht = 1.f - 2.f / (e + 1.f);          // tanh, overflow-safe
        float hn = (1.f - zreg[i]) * h_own[i] + zreg[i] * ht;
        h_own[i] = hn;
        cstore16(p.hb + (size_t)(rg * 16 + orow0 + i) * NHID + colN, f2b(hn));
      }
      if (t == TSTEPS - 1) {
#pragma unroll
        for (int i = 0; i < 4; ++i)
          p.h[(size_t)(rg * 16 + orow0 + i) * NHID + colN] = h_own[i];
      }
    }
    asm volatile("s_waitcnt vmcnt(0)" ::: "memory");
    __syncthreads();
    if (tid == 0) cstore32(myflag, 2 * t + 2);
  }
#undef STAGE
#undef LDSA
}

// out[c*R + r] = bf16(in[r*C + c])  (W[k][n] -> WT[n][k])
__global__ void k_transpose_bf16(const float* in, unsigned short* out, int R, int C) {
  int idx = blockIdx.x * 256 + threadIdx.x;
  if (idx < R * C) {
    int r = idx / C, c = idx % C;
    out[(size_t)c * R + r] = f2b(in[idx]);
  }
}

__global__ void k_convert_bf16(const float* in, unsigned short* out, int n) {
  for (int i = blockIdx.x * 256 + threadIdx.x; i < n; i += gridDim.x * 256)
    out[i] = f2b(in[i]);
}

// logits = h_final @ W_hy + b_y ; one block (64 lanes) per batch row
__global__ void k_logits(const float* __restrict__ h, const float* __restrict__ Why,
                         const float* __restrict__ by, float* __restrict__ out) {
  int row = blockIdx.x;
  int lane = threadIdx.x;
  float acc[10];
#pragma unroll
  for (int j = 0; j < 10; ++j) acc[j] = 0.f;
  for (int k = lane; k < NHID; k += 64) {
    float hv = h[row * NHID + k];
#pragma unroll
    for (int j = 0; j < 10; ++j) acc[j] += hv * Why[k * 10 + j];
  }
#pragma unroll
  for (int j = 0; j < 10; ++j)
    for (int off = 32; off; off >>= 1) acc[j] += __shfl_down(acc[j], off);
  if (lane == 0) {
#pragma unroll
    for (int j = 0; j < 10; ++j) out[row * 10 + j] = acc[j] + by[j];
  }
}

extern "C" void kernel_launch(void* const* d_in, const int* in_sizes, int n_in,
                              void* d_out, int out_size, void* d_ws, size_t ws_size,
                              hipStream_t stream) {
  (void)in_sizes; (void)n_in; (void)out_size; (void)ws_size;
  const float* u   = (const float*)d_in[0];
  const float* Wuz = (const float*)d_in[1];
  const float* Whz = (const float*)d_in[2];
  const float* bz  = (const float*)d_in[3];
  const float* Wur = (const float*)d_in[4];
  const float* Whr = (const float*)d_in[5];
  const float* br  = (const float*)d_in[6];
  const float* Wuh = (const float*)d_in[7];
  const float* Whh = (const float*)d_in[8];
  const float* bh  = (const float*)d_in[9];
  const float* Why = (const float*)d_in[10];
  const float* by  = (const float*)d_in[11];

  char* ws = (char*)d_ws;
  size_t off = 0;
  auto alloc = [&](size_t bytes) { char* p = ws + off; off += (bytes + 255) & ~255ull; return p; };
  unsigned short* WhzT = (unsigned short*)alloc((size_t)NHID * NHID * 2);
  unsigned short* WhrT = (unsigned short*)alloc((size_t)NHID * NHID * 2);
  unsigned short* WhhT = (unsigned short*)alloc((size_t)NHID * NHID * 2);
  unsigned short* WuzT = (unsigned short*)alloc((size_t)NHID * NIN * 2);
  unsigned short* WurT = (unsigned short*)alloc((size_t)NHID * NIN * 2);
  unsigned short* WuhT = (unsigned short*)alloc((size_t)NHID * NIN * 2);
  unsigned short* ub   = (unsigned short*)alloc((size_t)TSTEPS * NB * NIN * 2);
  unsigned short* hb   = (unsigned short*)alloc((size_t)NB * NHID * 2);
  unsigned short* sb   = (unsigned short*)alloc((size_t)NB * NHID * 2);
  unsigned* flags      = (unsigned*)alloc(4096);

  float* out = (float*)d_out;
  float* hf  = out + NB * 10;   // h_final region of d_out

  int n1 = NHID * NHID;
  hipLaunchKernelGGL(k_transpose_bf16, dim3((n1 + 255) / 256), dim3(256), 0, stream, Whz, WhzT, NHID, NHID);
  hipLaunchKernelGGL(k_transpose_bf16, dim3((n1 + 255) / 256), dim3(256), 0, stream, Whr, WhrT, NHID, NHID);
  hipLaunchKernelGGL(k_transpose_bf16, dim3((n1 + 255) / 256), dim3(256), 0, stream, Whh, WhhT, NHID, NHID);
  int n2 = NIN * NHID;
  hipLaunchKernelGGL(k_transpose_bf16, dim3((n2 + 255) / 256), dim3(256), 0, stream, Wuz, WuzT, NIN, NHID);
  hipLaunchKernelGGL(k_transpose_bf16, dim3((n2 + 255) / 256), dim3(256), 0, stream, Wur, WurT, NIN, NHID);
  hipLaunchKernelGGL(k_transpose_bf16, dim3((n2 + 255) / 256), dim3(256), 0, stream, Wuh, WuhT, NIN, NHID);
  int n3 = TSTEPS * NB * NIN;
  hipLaunchKernelGGL(k_convert_bf16, dim3(2048), dim3(256), 0, stream, u, ub, n3);
  hipMemsetAsync(hb, 0, (size_t)NB * NHID * 2, stream);   // h0 = 0
  hipMemsetAsync(flags, 0, 4096, stream);

  GruParams p;
  p.u = ub; p.WhzT = WhzT; p.WhrT = WhrT; p.WhhT = WhhT;
  p.WuzT = WuzT; p.WurT = WurT; p.WuhT = WuhT;
  p.bz = bz; p.br = br; p.bh = bh;
  p.h = hf; p.hb = hb; p.sb = sb;
  p.flags = flags;
  hipLaunchKernelGGL(gru_main, dim3(NBLK), dim3(NTHR), 0, stream, p);

  hipLaunchKernelGGL(k_logits, dim3(NB), dim3(64), 0, stream, hf, Why, by, out);
}

// Round 7
// 4797.291 us; speedup vs baseline: 8.4311x; 1.2188x over previous
//
#include <hip/hip_runtime.h>

#define NHID 1024
#define NB   128
#define NIN  64
#define TSTEPS 512
#define NBLK 256
#define NTHR 512
#define GROW 8          // batch rows per group

typedef __attribute__((ext_vector_type(8))) short short8v;
typedef __attribute__((ext_vector_type(4))) float f32x4;
typedef __attribute__((ext_vector_type(4))) unsigned u32x4;

__device__ __forceinline__ short8v ld8(const unsigned short* p) {
  return *reinterpret_cast<const short8v*>(p);
}

__device__ __forceinline__ unsigned short f2b(float x) {
  union { float f; unsigned u; } v; v.f = x;
  unsigned r = v.u + 0x7fffu + ((v.u >> 16) & 1u);
  return (unsigned short)(r >> 16);
}

// Agent-scope (coherence-point / MALL) relaxed atomics — proven protocol.
__device__ __forceinline__ unsigned cload32(const unsigned* p) {
  return __hip_atomic_load(p, __ATOMIC_RELAXED, __HIP_MEMORY_SCOPE_AGENT);
}
__device__ __forceinline__ void cstore16(unsigned short* p, unsigned short v) {
  __hip_atomic_store(p, v, __ATOMIC_RELAXED, __HIP_MEMORY_SCOPE_AGENT);
}
__device__ __forceinline__ void cstore32(unsigned* p, unsigned v) {
  __hip_atomic_store(p, v, __ATOMIC_RELAXED, __HIP_MEMORY_SCOPE_AGENT);
}

struct GruParams {
  const unsigned short* u;                    // [T][B][NIN] bf16
  const unsigned short* WhzT; const unsigned short* WhrT; const unsigned short* WhhT; // [n][k]
  const unsigned short* WuzT; const unsigned short* WurT; const unsigned short* WuhT; // [n][k]
  const float* bz; const float* br; const float* bh;
  float* h;                                   // [B][NHID] f32 — final h only
  unsigned short* hb;                         // bf16 h broadcast (coherent)
  unsigned short* sb;                         // bf16 r*h broadcast (coherent)
  unsigned* flags;                            // [16 groups][64 u32] phase flags
};

// Group barrier wait: wave 0's lanes 0..15 each watch one member's flag.
// Tight bound (1<<17): a broken rendezvous fast-fails at validation, no timeout.
__device__ __forceinline__ void group_wait(const unsigned* gflags, int lane, int w, unsigned pc) {
  if (w == 0) {
    const bool mine = lane < 16;
    const unsigned* fp = gflags + (mine ? lane : 0);
    for (int spin = 0; spin < (1 << 17); ++spin) {
      unsigned v = cload32(fp);
      if (__all((!mine) | (v >= pc))) break;
    }
  }
  __syncthreads();
}

// Block = 8 batch rows (rg of 16) x 64 hidden cols (cg of 16); 8 waves:
// ct = col-tile (4 x 16 cols), kh = K-half (2 x 512). 256 blocks, 1/CU.
// MFMA A-fragment rows 8..15 alias rows 0..7 (outputs unused).
__global__ __launch_bounds__(NTHR, 2) void gru_main(GruParams p) {
  __shared__ unsigned short stage[GROW * NHID];  // 16KB staged h/s rows (swizzled)
  __shared__ float red[2][4][4][64];             // K-half reduction, component-major

  const int tid  = threadIdx.x;
  const int lane = tid & 63;
  const int w    = tid >> 6;
  const int ct   = w & 3;
  const int kh   = w >> 2;
  const int rg   = blockIdx.x >> 4;   // 16 row groups (8 rows each)
  const int cg   = blockIdx.x & 15;   // 16 col groups (64 cols each)
  const int lr   = lane & 15;
  const int ar_  = lr & 7;            // aliased A-row for 8-row tiles
  const int lk   = (lane >> 4) * 8;

  const int colN = cg * 64 + ct * 16 + lr;
  const unsigned short* wz  = p.WhzT + (size_t)colN * NHID + kh * 512 + lk;
  const unsigned short* wr  = p.WhrT + (size_t)colN * NHID + kh * 512 + lk;
  const unsigned short* wh  = p.WhhT + (size_t)colN * NHID + kh * 512 + lk;
  const unsigned short* wuz = p.WuzT + colN * NIN + lk;
  const unsigned short* wur = p.WurT + colN * NIN + lk;
  const unsigned short* wuh = p.WuhT + colN * NIN + lk;

  const int orow0 = (lane >> 4) * 4;  // output row base; only orow0<8 is real
  const bool owner = orow0 < GROW;
  const float bzv = p.bz[colN];
  const float brv = p.br[colN];
  const float bhv = p.bh[colN];

  const unsigned short* hbR = p.hb + (size_t)rg * GROW * NHID;
  const unsigned short* sbR = p.sb + (size_t)rg * GROW * NHID;
  unsigned* gflags = p.flags + rg * 64;
  unsigned* myflag = gflags + cg;

  // Loop-invariant recurrent-weight B-fragments -> regs (fully static indexing;
  // partial unroll would demote to scratch — rule #20).
  short8v Wz[16], Wr[16], Wh[16];
#pragma unroll
  for (int it = 0; it < 16; ++it) {
    Wz[it] = ld8(wz + it * 32);
    Wr[it] = ld8(wr + it * 32);
    Wh[it] = ld8(wh + it * 32);
  }

  float h_own[4] = {0.f, 0.f, 0.f, 0.f};
  float zreg[4];

  // Stage 8 rows x 1024 cols bf16 = 1024 16B units; 512 thr x 2 units.
  // System-scope (sc0 sc1) dwordx4 loads: bypass L1/L2, coherent with the
  // producers' agent-scope stores; 2 transactions/thread (was 8).
#define STAGE(SRC)                                                               \
  {                                                                              \
    int j0 = tid, j1 = tid + NTHR;                                               \
    const void* g0 = (SRC) + (j0 >> 7) * NHID + (j0 & 127) * 8;                  \
    const void* g1 = (SRC) + (j1 >> 7) * NHID + (j1 & 127) * 8;                  \
    char* d0 = (char*)stage +                                                    \
               (((j0 >> 7) * 2048) | (((j0 & 127) * 16) ^ (((j0 >> 7) & 7) << 4)));\
    char* d1 = (char*)stage +                                                    \
               (((j1 >> 7) * 2048) | (((j1 & 127) * 16) ^ (((j1 >> 7) & 7) << 4)));\
    u32x4 v0, v1;                                                                \
    asm volatile("global_load_dwordx4 %0, %2, off sc0 sc1\n\t"                   \
                 "global_load_dwordx4 %1, %3, off sc0 sc1\n\t"                   \
                 "s_waitcnt vmcnt(0)"                                            \
                 : "=&v"(v0), "=&v"(v1) : "v"(g0), "v"(g1) : "memory");          \
    *(u32x4*)d0 = v0;                                                            \
    *(u32x4*)d1 = v1;                                                            \
  }

#define LDSA(IT)                                                                \
  (*(const short8v*)((const char*)stage +                                       \
     ((ar_ * 2048) | ((((kh * 512 + (IT) * 32 + lk) * 2)) ^ (ar_ << 4)))))

  for (int t = 0; t < TSTEPS; ++t) {
    const unsigned short* au = p.u + ((size_t)t * NB + rg * GROW + ar_) * NIN + lk;

    // ======== phase A: z, r ========
    f32x4 az = {0.f, 0.f, 0.f, 0.f};
    f32x4 ar = {0.f, 0.f, 0.f, 0.f};
    if (kh) {        // u-projection overlaps the group wait
#pragma unroll
      for (int it = 0; it < 2; ++it) {
        short8v a = ld8(au + it * 32);
        az = __builtin_amdgcn_mfma_f32_16x16x32_bf16(a, ld8(wuz + it * 32), az, 0, 0, 0);
        ar = __builtin_amdgcn_mfma_f32_16x16x32_bf16(a, ld8(wur + it * 32), ar, 0, 0, 0);
      }
    }
    group_wait(gflags, lane, w, 2 * t);      // h(t) ready (t=0: trivially)
    STAGE(hbR);
    __syncthreads();

#pragma unroll
    for (int it = 0; it < 16; ++it) {
      short8v a = LDSA(it);
      az = __builtin_amdgcn_mfma_f32_16x16x32_bf16(a, Wz[it], az, 0, 0, 0);
      ar = __builtin_amdgcn_mfma_f32_16x16x32_bf16(a, Wr[it], ar, 0, 0, 0);
    }
    if (kh) {
#pragma unroll
      for (int j = 0; j < 4; ++j) { red[0][ct][j][lane] = az[j]; red[1][ct][j][lane] = ar[j]; }
    }
    __syncthreads();
    if (!kh && owner) {
#pragma unroll
      for (int i = 0; i < 4; ++i) {
        float z = 1.f / (1.f + __expf(-(az[i] + red[0][ct][i][lane] + bzv)));
        float r = 1.f / (1.f + __expf(-(ar[i] + red[1][ct][i][lane] + brv)));
        zreg[i] = z;
        cstore16(p.sb + (size_t)(rg * GROW + orow0 + i) * NHID + colN, f2b(r * h_own[i]));
      }
    }
    asm volatile("s_waitcnt vmcnt(0)" ::: "memory");
    __syncthreads();
    if (tid == 0) cstore32(myflag, 2 * t + 1);

    // ======== phase B: h_tilde, h ========
    f32x4 ac = {0.f, 0.f, 0.f, 0.f};
    if (kh) {
#pragma unroll
      for (int it = 0; it < 2; ++it) {
        ac = __builtin_amdgcn_mfma_f32_16x16x32_bf16(ld8(au + it * 32), ld8(wuh + it * 32), ac, 0, 0, 0);
      }
    }
    group_wait(gflags, lane, w, 2 * t + 1);  // s(t) ready
    STAGE(sbR);
    __syncthreads();

#pragma unroll
    for (int it = 0; it < 16; ++it) {
      ac = __builtin_amdgcn_mfma_f32_16x16x32_bf16(LDSA(it), Wh[it], ac, 0, 0, 0);
    }
    if (kh) {
#pragma unroll
      for (int j = 0; j < 4; ++j) red[0][ct][j][lane] = ac[j];
    }
    __syncthreads();
    if (!kh && owner) {
#pragma unroll
      for (int i = 0; i < 4; ++i) {
        float x = ac[i] + red[0][ct][i][lane] + bhv;
        float e = __expf(2.f * x);
        float ht = 1.f - 2.f / (e + 1.f);          // tanh, overflow-safe
        float hn = (1.f - zreg[i]) * h_own[i] + zreg[i] * ht;
        h_own[i] = hn;
        cstore16(p.hb + (size_t)(rg * GROW + orow0 + i) * NHID + colN, f2b(hn));
      }
      if (t == TSTEPS - 1) {
#pragma unroll
        for (int i = 0; i < 4; ++i)
          p.h[(size_t)(rg * GROW + orow0 + i) * NHID + colN] = h_own[i];
      }
    }
    asm volatile("s_waitcnt vmcnt(0)" ::: "memory");
    __syncthreads();
    if (tid == 0) cstore32(myflag, 2 * t + 2);
  }
#undef STAGE
#undef LDSA
}

// out[c*R + r] = bf16(in[r*C + c])  (W[k][n] -> WT[n][k])
__global__ void k_transpose_bf16(const float* in, unsigned short* out, int R, int C) {
  int idx = blockIdx.x * 256 + threadIdx.x;
  if (idx < R * C) {
    int r = idx / C, c = idx % C;
    out[(size_t)c * R + r] = f2b(in[idx]);
  }
}

__global__ void k_convert_bf16(const float* in, unsigned short* out, int n) {
  for (int i = blockIdx.x * 256 + threadIdx.x; i < n; i += gridDim.x * 256)
    out[i] = f2b(in[i]);
}

// logits = h_final @ W_hy + b_y ; one block (64 lanes) per batch row
__global__ void k_logits(const float* __restrict__ h, const float* __restrict__ Why,
                         const float* __restrict__ by, float* __restrict__ out) {
  int row = blockIdx.x;
  int lane = threadIdx.x;
  float acc[10];
#pragma unroll
  for (int j = 0; j < 10; ++j) acc[j] = 0.f;
  for (int k = lane; k < NHID; k += 64) {
    float hv = h[row * NHID + k];
#pragma unroll
    for (int j = 0; j < 10; ++j) acc[j] += hv * Why[k * 10 + j];
  }
#pragma unroll
  for (int j = 0; j < 10; ++j)
    for (int off = 32; off; off >>= 1) acc[j] += __shfl_down(acc[j], off);
  if (lane == 0) {
#pragma unroll
    for (int j = 0; j < 10; ++j) out[row * 10 + j] = acc[j] + by[j];
  }
}

extern "C" void kernel_launch(void* const* d_in, const int* in_sizes, int n_in,
                              void* d_out, int out_size, void* d_ws, size_t ws_size,
                              hipStream_t stream) {
  (void)in_sizes; (void)n_in; (void)out_size; (void)ws_size;
  const float* u   = (const float*)d_in[0];
  const float* Wuz = (const float*)d_in[1];
  const float* Whz = (const float*)d_in[2];
  const float* bz  = (const float*)d_in[3];
  const float* Wur = (const float*)d_in[4];
  const float* Whr = (const float*)d_in[5];
  const float* br  = (const float*)d_in[6];
  const float* Wuh = (const float*)d_in[7];
  const float* Whh = (const float*)d_in[8];
  const float* bh  = (const float*)d_in[9];
  const float* Why = (const float*)d_in[10];
  const float* by  = (const float*)d_in[11];

  char* ws = (char*)d_ws;
  size_t off = 0;
  auto alloc = [&](size_t bytes) { char* p = ws + off; off += (bytes + 255) & ~255ull; return p; };
  unsigned short* WhzT = (unsigned short*)alloc((size_t)NHID * NHID * 2);
  unsigned short* WhrT = (unsigned short*)alloc((size_t)NHID * NHID * 2);
  unsigned short* WhhT = (unsigned short*)alloc((size_t)NHID * NHID * 2);
  unsigned short* WuzT = (unsigned short*)alloc((size_t)NHID * NIN * 2);
  unsigned short* WurT = (unsigned short*)alloc((size_t)NHID * NIN * 2);
  unsigned short* WuhT = (unsigned short*)alloc((size_t)NHID * NIN * 2);
  unsigned short* ub   = (unsigned short*)alloc((size_t)TSTEPS * NB * NIN * 2);
  unsigned short* hb   = (unsigned short*)alloc((size_t)NB * NHID * 2);
  unsigned short* sb   = (unsigned short*)alloc((size_t)NB * NHID * 2);
  unsigned* flags      = (unsigned*)alloc(4096);   // 16 groups x 64 u32

  float* out = (float*)d_out;
  float* hf  = out + NB * 10;   // h_final region of d_out

  int n1 = NHID * NHID;
  hipLaunchKernelGGL(k_transpose_bf16, dim3((n1 + 255) / 256), dim3(256), 0, stream, Whz, WhzT, NHID, NHID);
  hipLaunchKernelGGL(k_transpose_bf16, dim3((n1 + 255) / 256), dim3(256), 0, stream, Whr, WhrT, NHID, NHID);
  hipLaunchKernelGGL(k_transpose_bf16, dim3((n1 + 255) / 256), dim3(256), 0, stream, Whh, WhhT, NHID, NHID);
  int n2 = NIN * NHID;
  hipLaunchKernelGGL(k_transpose_bf16, dim3((n2 + 255) / 256), dim3(256), 0, stream, Wuz, WuzT, NIN, NHID);
  hipLaunchKernelGGL(k_transpose_bf16, dim3((n2 + 255) / 256), dim3(256), 0, stream, Wur, WurT, NIN, NHID);
  hipLaunchKernelGGL(k_transpose_bf16, dim3((n2 + 255) / 256), dim3(256), 0, stream, Wuh, WuhT, NIN, NHID);
  int n3 = TSTEPS * NB * NIN;
  hipLaunchKernelGGL(k_convert_bf16, dim3(2048), dim3(256), 0, stream, u, ub, n3);
  hipMemsetAsync(hb, 0, (size_t)NB * NHID * 2, stream);   // h0 = 0
  hipMemsetAsync(flags, 0, 4096, stream);

  GruParams p;
  p.u = ub; p.WhzT = WhzT; p.WhrT = WhrT; p.WhhT = WhhT;
  p.WuzT = WuzT; p.WurT = WurT; p.WuhT = WuhT;
  p.bz = bz; p.br = br; p.bh = bh;
  p.h = hf; p.hb = hb; p.sb = sb;
  p.flags = flags;
  hipLaunchKernelGGL(gru_main, dim3(NBLK), dim3(NTHR), 0, stream, p);

  hipLaunchKernelGGL(k_logits, dim3(NB), dim3(64), 0, stream, hf, Why, by, out);
}

// Round 8
// 3705.665 us; speedup vs baseline: 10.9148x; 1.2946x over previous
//
#include <hip/hip_runtime.h>

#define NHID 1024
#define NB   128
#define NIN  64
#define TSTEPS 512
#define NBLK 256
#define NTHR 512
#define GROW 8                  // batch rows per group
#define SLOTN (NB * NHID)       // elements per exchange slot

typedef __attribute__((ext_vector_type(8))) short short8v;
typedef __attribute__((ext_vector_type(4))) float f32x4;
typedef __attribute__((ext_vector_type(4))) unsigned u32x4;

__device__ __forceinline__ short8v ld8(const unsigned short* p) {
  return *reinterpret_cast<const short8v*>(p);
}

__device__ __forceinline__ unsigned short f2b(float x) {
  union { float f; unsigned u; } v; v.f = x;
  unsigned r = v.u + 0x7fffu + ((v.u >> 16) & 1u);
  return (unsigned short)(r >> 16);
}

// Agent-scope (MALL) relaxed atomic store for exchange data (2B granules).
__device__ __forceinline__ void cstore16(unsigned short* p, unsigned short v) {
  __hip_atomic_store(p, v, __ATOMIC_RELAXED, __HIP_MEMORY_SCOPE_AGENT);
}

// Unit validity: no bf16 lane equals the poison pattern 0xFFFF. Real |h|,|s| < 1
// so f2b never emits 0xFFFF — poison is unforgeable.
__device__ __forceinline__ bool ok16(u32x4 v) {
  unsigned bad = 0;
#pragma unroll
  for (int i = 0; i < 4; ++i) {
    bad |= (unsigned)((v[i] & 0xFFFFu) == 0xFFFFu);
    bad |= (unsigned)((v[i] >> 16) == 0xFFFFu);
  }
  return bad == 0;
}

struct GruParams {
  const unsigned short* u;                    // [T][B][NIN] bf16
  const unsigned short* WhzT; const unsigned short* WhrT; const unsigned short* WhhT; // [n][k]
  const unsigned short* WuzT; const unsigned short* WurT; const unsigned short* WuhT; // [n][k]
  const float* bz; const float* br; const float* bh;
  float* h;                                   // [B][NHID] f32 — final h only
  unsigned short* hb;                         // [4][B][NHID] bf16 h slots (poison-synced)
  unsigned short* sb;                         // [4][B][NHID] bf16 r*h slots (poison-synced)
};

// Block = 8 batch rows (rg of 16) x 64 hidden cols (cg of 16); 8 waves:
// ct = col-tile (4 x 16 cols), kh = K-half (2 x 512). 256 blocks, 1/CU.
// Sync = data itself: poll exchange units until poison gone. No flags.
__global__ __launch_bounds__(NTHR, 2) void gru_main(GruParams p) {
  __shared__ unsigned short stage[GROW * NHID];  // 16KB staged h/s rows (swizzled)
  __shared__ float red[2][4][4][64];             // K-half reduction, component-major

  const int tid  = threadIdx.x;
  const int lane = tid & 63;
  const int w    = tid >> 6;
  const int ct   = w & 3;
  const int kh   = w >> 2;
  const int rg   = blockIdx.x >> 4;   // 16 row groups (8 rows each)
  const int cg   = blockIdx.x & 15;   // 16 col groups (64 cols each)
  const int lr   = lane & 15;
  const int ar_  = lr & 7;            // aliased A-row for 8-row tiles
  const int lk   = (lane >> 4) * 8;

  const int colN = cg * 64 + ct * 16 + lr;
  const unsigned short* wz  = p.WhzT + (size_t)colN * NHID + kh * 512 + lk;
  const unsigned short* wr  = p.WhrT + (size_t)colN * NHID + kh * 512 + lk;
  const unsigned short* wh  = p.WhhT + (size_t)colN * NHID + kh * 512 + lk;
  const unsigned short* wuz = p.WuzT + colN * NIN + lk;
  const unsigned short* wur = p.WurT + colN * NIN + lk;
  const unsigned short* wuh = p.WuhT + colN * NIN + lk;

  const int orow0 = (lane >> 4) * 4;  // output row base; only orow0<8 is real
  const bool owner = orow0 < GROW;
  const float bzv = p.bz[colN];
  const float brv = p.br[colN];
  const float bhv = p.bh[colN];

  const u32x4 poisonv = {0xFFFFFFFFu, 0xFFFFFFFFu, 0xFFFFFFFFu, 0xFFFFFFFFu};

  // Loop-invariant recurrent-weight B-fragments (static indexing only — rule #20).
  short8v Wz[16], Wr[16], Wh[16];
#pragma unroll
  for (int it = 0; it < 16; ++it) {
    Wz[it] = ld8(wz + it * 32);
    Wr[it] = ld8(wr + it * 32);
    Wh[it] = ld8(wh + it * 32);
  }

  float h_own[4] = {0.f, 0.f, 0.f, 0.f};
  float zreg[4];

  // Poll-stage: load 2x16B units/thread from a slot slice until non-poison,
  // then write swizzled LDS. Tearing-safe: partial writes still show poison.
#define PSTAGE(SRC)                                                              \
  {                                                                              \
    int j0 = tid, j1 = tid + NTHR;                                               \
    const void* g0 = (SRC) + (j0 >> 7) * NHID + (j0 & 127) * 8;                  \
    const void* g1 = (SRC) + (j1 >> 7) * NHID + (j1 & 127) * 8;                  \
    char* d0 = (char*)stage +                                                    \
               (((j0 >> 7) * 2048) | (((j0 & 127) * 16) ^ (((j0 >> 7) & 7) << 4)));\
    char* d1 = (char*)stage +                                                    \
               (((j1 >> 7) * 2048) | (((j1 & 127) * 16) ^ (((j1 >> 7) & 7) << 4)));\
    u32x4 v0 = poisonv, v1 = poisonv;                                            \
    bool k0 = false, k1 = false;                                                 \
    for (int spin = 0; spin < (1 << 13); ++spin) {                               \
      if (!k0) asm volatile("global_load_dwordx4 %0, %1, off sc0 sc1"            \
                            : "=v"(v0) : "v"(g0) : "memory");                    \
      if (!k1) asm volatile("global_load_dwordx4 %0, %1, off sc0 sc1"            \
                            : "=v"(v1) : "v"(g1) : "memory");                    \
      asm volatile("s_waitcnt vmcnt(0)" ::: "memory");                           \
      k0 = k0 || ok16(v0);                                                       \
      k1 = k1 || ok16(v1);                                                       \
      if (k0 && k1) break;                                                       \
    }                                                                            \
    *(u32x4*)d0 = v0;                                                            \
    *(u32x4*)d1 = v1;                                                            \
  }

  // Re-poison own 64-col slice (8 rows) of a consumed slot: 64 x 16B units.
#define REPOISON(SLOTSLICE)                                                      \
  if (tid < 64) {                                                                \
    void* rp = (SLOTSLICE) + (tid >> 3) * NHID + cg * 64 + (tid & 7) * 8;        \
    asm volatile("global_store_dwordx4 %0, %1, off sc0 sc1"                      \
                 :: "v"(rp), "v"(poisonv) : "memory");                           \
  }

#define LDSA(IT)                                                                \
  (*(const short8v*)((const char*)stage +                                       \
     ((ar_ * 2048) | ((((kh * 512 + (IT) * 32 + lk) * 2)) ^ (ar_ << 4)))))

  for (int t = 0; t < TSTEPS; ++t) {
    const int sA = t & 3;          // slot holding h(t) / receiving s(t)
    const int sP = (t + 3) & 3;    // slot to re-poison (provably consumed)
    const int sW = (t + 1) & 3;    // slot receiving h(t+1)
    const unsigned short* au = p.u + ((size_t)t * NB + rg * GROW + ar_) * NIN + lk;

    // ======== phase A: z, r, s = r*h ========
    f32x4 az = {0.f, 0.f, 0.f, 0.f};
    f32x4 ar = {0.f, 0.f, 0.f, 0.f};
    if (kh) {        // u-projection overlaps the data poll
#pragma unroll
      for (int it = 0; it < 2; ++it) {
        short8v a = ld8(au + it * 32);
        az = __builtin_amdgcn_mfma_f32_16x16x32_bf16(a, ld8(wuz + it * 32), az, 0, 0, 0);
        ar = __builtin_amdgcn_mfma_f32_16x16x32_bf16(a, ld8(wur + it * 32), ar, 0, 0, 0);
      }
    }
    PSTAGE(p.hb + sA * SLOTN + rg * GROW * NHID);        // h(t) poll+stage
    REPOISON(p.sb + sP * SLOTN + rg * GROW * NHID);      // retire s slot t+3
    asm volatile("s_waitcnt vmcnt(0)" ::: "memory");     // re-poison at MALL
    __syncthreads();                                     // ... before any data store

#pragma unroll
    for (int it = 0; it < 16; ++it) {
      short8v a = LDSA(it);
      az = __builtin_amdgcn_mfma_f32_16x16x32_bf16(a, Wz[it], az, 0, 0, 0);
      ar = __builtin_amdgcn_mfma_f32_16x16x32_bf16(a, Wr[it], ar, 0, 0, 0);
    }
    if (kh) {
#pragma unroll
      for (int j = 0; j < 4; ++j) { red[0][ct][j][lane] = az[j]; red[1][ct][j][lane] = ar[j]; }
    }
    __syncthreads();
    if (!kh && owner) {
#pragma unroll
      for (int i = 0; i < 4; ++i) {
        float z = 1.f / (1.f + __expf(-(az[i] + red[0][ct][i][lane] + bzv)));
        float r = 1.f / (1.f + __expf(-(ar[i] + red[1][ct][i][lane] + brv)));
        zreg[i] = z;
        cstore16(p.sb + sA * SLOTN + (size_t)(rg * GROW + orow0 + i) * NHID + colN,
                 f2b(r * h_own[i]));
      }
    }

    // ======== phase B: h_tilde, h(t+1) ========
    f32x4 ac = {0.f, 0.f, 0.f, 0.f};
    if (kh) {
#pragma unroll
      for (int it = 0; it < 2; ++it) {
        ac = __builtin_amdgcn_mfma_f32_16x16x32_bf16(ld8(au + it * 32), ld8(wuh + it * 32), ac, 0, 0, 0);
      }
    }
    PSTAGE(p.sb + sA * SLOTN + rg * GROW * NHID);        // s(t) poll+stage
    REPOISON(p.hb + sP * SLOTN + rg * GROW * NHID);      // retire h slot t+3
    asm volatile("s_waitcnt vmcnt(0)" ::: "memory");
    __syncthreads();

#pragma unroll
    for (int it = 0; it < 16; ++it) {
      ac = __builtin_amdgcn_mfma_f32_16x16x32_bf16(LDSA(it), Wh[it], ac, 0, 0, 0);
    }
    if (kh) {
#pragma unroll
      for (int j = 0; j < 4; ++j) red[0][ct][j][lane] = ac[j];
    }
    __syncthreads();
    if (!kh && owner) {
#pragma unroll
      for (int i = 0; i < 4; ++i) {
        float x = ac[i] + red[0][ct][i][lane] + bhv;
        float e = __expf(2.f * x);
        float ht = 1.f - 2.f / (e + 1.f);          // tanh, overflow-safe
        float hn = (1.f - zreg[i]) * h_own[i] + zreg[i] * ht;
        h_own[i] = hn;
        cstore16(p.hb + sW * SLOTN + (size_t)(rg * GROW + orow0 + i) * NHID + colN, f2b(hn));
      }
      if (t == TSTEPS - 1) {
#pragma unroll
        for (int i = 0; i < 4; ++i)
          p.h[(size_t)(rg * GROW + orow0 + i) * NHID + colN] = h_own[i];
      }
    }
  }
#undef PSTAGE
#undef REPOISON
#undef LDSA
}

// out[c*R + r] = bf16(in[r*C + c])  (W[k][n] -> WT[n][k])
__global__ void k_transpose_bf16(const float* in, unsigned short* out, int R, int C) {
  int idx = blockIdx.x * 256 + threadIdx.x;
  if (idx < R * C) {
    int r = idx / C, c = idx % C;
    out[(size_t)c * R + r] = f2b(in[idx]);
  }
}

__global__ void k_convert_bf16(const float* in, unsigned short* out, int n) {
  for (int i = blockIdx.x * 256 + threadIdx.x; i < n; i += gridDim.x * 256)
    out[i] = f2b(in[i]);
}

// logits = h_final @ W_hy + b_y ; one block (64 lanes) per batch row
__global__ void k_logits(const float* __restrict__ h, const float* __restrict__ Why,
                         const float* __restrict__ by, float* __restrict__ out) {
  int row = blockIdx.x;
  int lane = threadIdx.x;
  float acc[10];
#pragma unroll
  for (int j = 0; j < 10; ++j) acc[j] = 0.f;
  for (int k = lane; k < NHID; k += 64) {
    float hv = h[row * NHID + k];
#pragma unroll
    for (int j = 0; j < 10; ++j) acc[j] += hv * Why[k * 10 + j];
  }
#pragma unroll
  for (int j = 0; j < 10; ++j)
    for (int off = 32; off; off >>= 1) acc[j] += __shfl_down(acc[j], off);
  if (lane == 0) {
#pragma unroll
    for (int j = 0; j < 10; ++j) out[row * 10 + j] = acc[j] + by[j];
  }
}

extern "C" void kernel_launch(void* const* d_in, const int* in_sizes, int n_in,
                              void* d_out, int out_size, void* d_ws, size_t ws_size,
                              hipStream_t stream) {
  (void)in_sizes; (void)n_in; (void)out_size; (void)ws_size;
  const float* u   = (const float*)d_in[0];
  const float* Wuz = (const float*)d_in[1];
  const float* Whz = (const float*)d_in[2];
  const float* bz  = (const float*)d_in[3];
  const float* Wur = (const float*)d_in[4];
  const float* Whr = (const float*)d_in[5];
  const float* br  = (const float*)d_in[6];
  const float* Wuh = (const float*)d_in[7];
  const float* Whh = (const float*)d_in[8];
  const float* bh  = (const float*)d_in[9];
  const float* Why = (const float*)d_in[10];
  const float* by  = (const float*)d_in[11];

  char* ws = (char*)d_ws;
  size_t off = 0;
  auto alloc = [&](size_t bytes) { char* p = ws + off; off += (bytes + 255) & ~255ull; return p; };
  unsigned short* WhzT = (unsigned short*)alloc((size_t)NHID * NHID * 2);
  unsigned short* WhrT = (unsigned short*)alloc((size_t)NHID * NHID * 2);
  unsigned short* WhhT = (unsigned short*)alloc((size_t)NHID * NHID * 2);
  unsigned short* WuzT = (unsigned short*)alloc((size_t)NHID * NIN * 2);
  unsigned short* WurT = (unsigned short*)alloc((size_t)NHID * NIN * 2);
  unsigned short* WuhT = (unsigned short*)alloc((size_t)NHID * NIN * 2);
  unsigned short* ub   = (unsigned short*)alloc((size_t)TSTEPS * NB * NIN * 2);
  unsigned short* hb   = (unsigned short*)alloc(4ull * SLOTN * 2);
  unsigned short* sb   = (unsigned short*)alloc(4ull * SLOTN * 2);

  float* out = (float*)d_out;
  float* hf  = out + NB * 10;   // h_final region of d_out

  int n1 = NHID * NHID;
  hipLaunchKernelGGL(k_transpose_bf16, dim3((n1 + 255) / 256), dim3(256), 0, stream, Whz, WhzT, NHID, NHID);
  hipLaunchKernelGGL(k_transpose_bf16, dim3((n1 + 255) / 256), dim3(256), 0, stream, Whr, WhrT, NHID, NHID);
  hipLaunchKernelGGL(k_transpose_bf16, dim3((n1 + 255) / 256), dim3(256), 0, stream, Whh, WhhT, NHID, NHID);
  int n2 = NIN * NHID;
  hipLaunchKernelGGL(k_transpose_bf16, dim3((n2 + 255) / 256), dim3(256), 0, stream, Wuz, WuzT, NIN, NHID);
  hipLaunchKernelGGL(k_transpose_bf16, dim3((n2 + 255) / 256), dim3(256), 0, stream, Wur, WurT, NIN, NHID);
  hipLaunchKernelGGL(k_transpose_bf16, dim3((n2 + 255) / 256), dim3(256), 0, stream, Wuh, WuhT, NIN, NHID);
  int n3 = TSTEPS * NB * NIN;
  hipLaunchKernelGGL(k_convert_bf16, dim3(2048), dim3(256), 0, stream, u, ub, n3);
  // Slot init each launch (deterministic under graph replay):
  // hb slot 0 = real h0 = 0; hb slots 1-3 and all sb slots = 0xFFFF poison.
  hipMemsetAsync(hb, 0, (size_t)SLOTN * 2, stream);
  hipMemsetAsync(hb + SLOTN, 0xFF, 3ull * SLOTN * 2, stream);
  hipMemsetAsync(sb, 0xFF, 4ull * SLOTN * 2, stream);

  GruParams p;
  p.u = ub; p.WhzT = WhzT; p.WhrT = WhrT; p.WhhT = WhhT;
  p.WuzT = WuzT; p.WurT = WurT; p.WuhT = WuhT;
  p.bz = bz; p.br = br; p.bh = bh;
  p.h = hf; p.hb = hb; p.sb = sb;
  hipLaunchKernelGGL(gru_main, dim3(NBLK), dim3(NTHR), 0, stream, p);

  hipLaunchKernelGGL(k_logits, dim3(NB), dim3(64), 0, stream, hf, Why, by, out);
}